// Round 3
// baseline (16677.762 us; speedup 1.0000x reference)
//
#include <hip/hip_runtime.h>
#include <cfloat>

#define N_ROWS 65536
#define DIM 256
#define K_CODES 2048
#define MT 64      // rows per block
#define KT 256     // codes per k-tile
#define DC 8       // d-chunk staged in LDS (small => low LDS => high occupancy)
#define BLOCK 256
#define ZSTR 68            // padded row stride for zS (floats)
#define ESTR 260           // padded row stride for eT (floats)
#define DCHUNKS (DIM / DC)                    // 32
#define NSTAGES (DCHUNKS * (K_CODES / KT))    // 256

// ---------------- e_sq precompute: one wave per code ----------------
__global__ __launch_bounds__(256)
void vq_esq_kernel(const float* __restrict__ emb, float* __restrict__ esq) {
    int w = threadIdx.x >> 6;
    int lane = threadIdx.x & 63;
    int k = blockIdx.x * 4 + w;
    float4 v = *(const float4*)&emb[(size_t)k * DIM + lane * 4];
    float s = v.x * v.x + v.y * v.y + v.z * v.z + v.w * v.w;
    #pragma unroll
    for (int off = 32; off >= 1; off >>= 1) s += __shfl_xor(s, off, 64);
    if (lane == 0) esq[k] = s;
}

// ---------------- main fused kernel ----------------
// DC=8 keeps LDS at ~21.5 KB so ~6 blocks/CU are resident; cross-block waves
// hide the per-stage barrier. Thread (rg,cg) owns rows {8rg..8rg+7} x codes
// {kt+4cg+i} u {kt+128+4cg+i}; eT reads lane-contiguous (conflict-free).
__global__ __launch_bounds__(BLOCK, 6)
void vq_main_kernel(const float* __restrict__ z,
                    const float* __restrict__ emb,
                    const float* __restrict__ esq,
                    float* __restrict__ out,
                    float* __restrict__ loss_acc) {
    __shared__ float zS[2][DC][ZSTR];
    __shared__ float eT[2][DC][ESTR];
    __shared__ float zsq_s[MT];
    __shared__ int   best_s[MT];
    __shared__ float lred[4];

    const int tid = threadIdx.x;
    const int m0  = blockIdx.x * MT;
    const int rg  = tid >> 5;   // 0..7  : rows 8*rg..8*rg+7
    const int cg  = tid & 31;   // 0..31 : codes 4*cg(+128)
    const int s1  = tid & 1;    // staging float4 slot within 8-d chunk
    const int sc  = tid >> 1;   // staging code (0..127) / z-row (0..63 for tid<128)

    // ---- z_sq for the block's 64 rows (4 threads per row) ----
    {
        int r = tid >> 2, q = tid & 3;
        const float* zr = &z[(size_t)(m0 + r) * DIM + q * 64];
        float s = 0.f;
        #pragma unroll
        for (int d4 = 0; d4 < 16; ++d4) {
            float4 v = *(const float4*)&zr[d4 * 4];
            s += v.x * v.x; s += v.y * v.y; s += v.z * v.z; s += v.w * v.w;
        }
        s += __shfl_down(s, 2, 64);
        s += __shfl_down(s, 1, 64);
        if (q == 0) zsq_s[r] = s;
    }

    // ---- stage 0 into buffer 0 ----
    {
        float4 e0 = *(const float4*)&emb[(size_t)(sc      ) * DIM + 4 * s1];
        float4 e1 = *(const float4*)&emb[(size_t)(sc + 128) * DIM + 4 * s1];
        eT[0][4 * s1 + 0][sc      ] = e0.x;
        eT[0][4 * s1 + 1][sc      ] = e0.y;
        eT[0][4 * s1 + 2][sc      ] = e0.z;
        eT[0][4 * s1 + 3][sc      ] = e0.w;
        eT[0][4 * s1 + 0][sc + 128] = e1.x;
        eT[0][4 * s1 + 1][sc + 128] = e1.y;
        eT[0][4 * s1 + 2][sc + 128] = e1.z;
        eT[0][4 * s1 + 3][sc + 128] = e1.w;
        if (tid < 128) {
            float4 zv = *(const float4*)&z[(size_t)(m0 + sc) * DIM + 4 * s1];
            zS[0][4 * s1 + 0][sc] = zv.x;
            zS[0][4 * s1 + 1][sc] = zv.y;
            zS[0][4 * s1 + 2][sc] = zv.z;
            zS[0][4 * s1 + 3][sc] = zv.w;
        }
    }
    __syncthreads();

    float bestv[8];
    int   besti[8];
    #pragma unroll
    for (int j = 0; j < 8; ++j) { bestv[j] = FLT_MAX; besti[j] = 0; }

    float acc[8][8];

    for (int s = 0; s < NSTAGES; ++s) {
        const int p     = s & 1;
        const int kt    = (s >> 5) * KT;
        const int dcIdx = s & (DCHUNKS - 1);

        if (dcIdx == 0) {
            #pragma unroll
            for (int j = 0; j < 8; ++j)
                #pragma unroll
                for (int i = 0; i < 8; ++i) acc[j][i] = 0.f;
        }

        // ---- prefetch stage s+1 (global -> regs); uniform clamp on last ----
        const int sn  = (s + 1 < NSTAGES) ? s + 1 : s;
        const int nkt = (sn >> 5) * KT;
        const int ndc = (sn & (DCHUNKS - 1)) * DC;
        float4 en0 = *(const float4*)&emb[(size_t)(nkt + sc      ) * DIM + ndc + 4 * s1];
        float4 en1 = *(const float4*)&emb[(size_t)(nkt + sc + 128) * DIM + ndc + 4 * s1];
        float4 zn;
        if (tid < 128)
            zn = *(const float4*)&z[(size_t)(m0 + sc) * DIM + ndc + 4 * s1];

        // ---- compute stage s ----
        #pragma unroll
        for (int d = 0; d < DC; ++d) {
            float4 a0 = *(const float4*)&zS[p][d][8 * rg];
            float4 a1 = *(const float4*)&zS[p][d][8 * rg + 4];
            float4 b0 = *(const float4*)&eT[p][d][4 * cg];
            float4 b1 = *(const float4*)&eT[p][d][128 + 4 * cg];
            float a[8] = {a0.x, a0.y, a0.z, a0.w, a1.x, a1.y, a1.z, a1.w};
            float b[8] = {b0.x, b0.y, b0.z, b0.w, b1.x, b1.y, b1.z, b1.w};
            #pragma unroll
            for (int j = 0; j < 8; ++j)
                #pragma unroll
                for (int i = 0; i < 8; ++i)
                    acc[j][i] = fmaf(a[j], b[i], acc[j][i]);
        }

        // ---- write prefetched stage into the other buffer ----
        {
            const int q = p ^ 1;
            eT[q][4 * s1 + 0][sc      ] = en0.x;
            eT[q][4 * s1 + 1][sc      ] = en0.y;
            eT[q][4 * s1 + 2][sc      ] = en0.z;
            eT[q][4 * s1 + 3][sc      ] = en0.w;
            eT[q][4 * s1 + 0][sc + 128] = en1.x;
            eT[q][4 * s1 + 1][sc + 128] = en1.y;
            eT[q][4 * s1 + 2][sc + 128] = en1.z;
            eT[q][4 * s1 + 3][sc + 128] = en1.w;
            if (tid < 128) {
                zS[q][4 * s1 + 0][sc] = zn.x;
                zS[q][4 * s1 + 1][sc] = zn.y;
                zS[q][4 * s1 + 2][sc] = zn.z;
                zS[q][4 * s1 + 3][sc] = zn.w;
            }
        }

        // ---- end of k-tile: literal f32 distance + running argmin ----
        if (dcIdx == DCHUNKS - 1) {
            float4 e0 = *(const float4*)&esq[kt + 4 * cg];
            float4 e1 = *(const float4*)&esq[kt + 128 + 4 * cg];
            float es[8] = {e0.x, e0.y, e0.z, e0.w, e1.x, e1.y, e1.z, e1.w};
            #pragma unroll
            for (int j = 0; j < 8; ++j) {
                float zs = zsq_s[8 * rg + j];
                #pragma unroll
                for (int i = 0; i < 8; ++i) {
                    float t    = zs + es[i];             // fl(z_sq + e_sq)
                    float dist = t - 2.0f * acc[j][i];   // fl(t - 2*cross)
                    int idx = (i < 4) ? (kt + 4 * cg + i) : (kt + 128 + 4 * cg + (i - 4));
                    bool better = (dist < bestv[j]);
                    bestv[j] = better ? dist : bestv[j];
                    besti[j] = better ? idx  : besti[j];
                }
            }
        }
        __syncthreads();
    }

    // cross-lane argmin over the 32 code-group lanes (lexicographic: val, idx)
    #pragma unroll
    for (int off = 16; off >= 1; off >>= 1) {
        #pragma unroll
        for (int j = 0; j < 8; ++j) {
            float ov = __shfl_xor(bestv[j], off, 64);
            int   oi = __shfl_xor(besti[j], off, 64);
            bool take = (ov < bestv[j]) || (ov == bestv[j] && oi < besti[j]);
            bestv[j] = take ? ov : bestv[j];
            besti[j] = take ? oi : besti[j];
        }
    }
    if (cg == 0) {
        #pragma unroll
        for (int j = 0; j < 8; ++j) best_s[8 * rg + j] = besti[j];
    }
    __syncthreads();

    // ---- epilogue: z_q_st (straight-through), loss partial, indices ----
    float lsum = 0.f;
    const int d4 = tid & 63;
    for (int it = 0; it < 16; ++it) {
        int r  = (tid >> 6) + it * 4;
        int bk = best_s[r];
        float4 q4 = *(const float4*)&emb[(size_t)bk * DIM + 4 * d4];
        float4 z4 = *(const float4*)&z[(size_t)(m0 + r) * DIM + 4 * d4];
        float4 o;
        float dx;
        dx = q4.x - z4.x; o.x = z4.x + dx; lsum = fmaf(dx, dx, lsum);
        dx = q4.y - z4.y; o.y = z4.y + dx; lsum = fmaf(dx, dx, lsum);
        dx = q4.z - z4.z; o.z = z4.z + dx; lsum = fmaf(dx, dx, lsum);
        dx = q4.w - z4.w; o.w = z4.w + dx; lsum = fmaf(dx, dx, lsum);
        *(float4*)&out[(size_t)(m0 + r) * DIM + 4 * d4] = o;
    }
    #pragma unroll
    for (int off = 32; off >= 1; off >>= 1) lsum += __shfl_xor(lsum, off, 64);
    if ((tid & 63) == 0) lred[tid >> 6] = lsum;
    __syncthreads();
    if (tid == 0) {
        float bs = lred[0] + lred[1] + lred[2] + lred[3];
        atomicAdd(loss_acc, bs);
    }
    // indices as float32 values
    if (tid < MT) out[(size_t)N_ROWS * DIM + 1 + m0 + tid] = (float)best_s[tid];
}

// ---------------- finalize: vq_loss = 1.25 * mean ----------------
__global__ void vq_finalize_kernel(const float* __restrict__ loss_acc,
                                   float* __restrict__ out) {
    double s = (double)loss_acc[0];
    out[(size_t)N_ROWS * DIM] = (float)(s * 1.25 / ((double)N_ROWS * (double)DIM));
}

extern "C" void kernel_launch(void* const* d_in, const int* in_sizes, int n_in,
                              void* d_out, int out_size, void* d_ws, size_t ws_size,
                              hipStream_t stream) {
    (void)in_sizes; (void)n_in; (void)out_size; (void)ws_size;
    const float* z   = (const float*)d_in[0];
    const float* emb = (const float*)d_in[1];
    float* out = (float*)d_out;
    float* ws  = (float*)d_ws;
    float* loss_acc = ws;        // ws[0]
    float* esq      = ws + 64;   // 2048 floats

    hipMemsetAsync(d_ws, 0, sizeof(float), stream);
    vq_esq_kernel<<<K_CODES / 4, 256, 0, stream>>>(emb, esq);
    vq_main_kernel<<<N_ROWS / MT, BLOCK, 0, stream>>>(z, emb, esq, out, loss_acc);
    vq_finalize_kernel<<<1, 1, 0, stream>>>(loss_acc, out);
}

// Round 4
// 10156.103 us; speedup vs baseline: 1.6421x; 1.6421x over previous
//
#include <hip/hip_runtime.h>
#include <cfloat>

#define N_ROWS 65536
#define DIM 256
#define K_CODES 2048
#define MT 64      // rows per block
#define KT 256     // codes per k-tile
#define DC 8       // d-chunk staged in LDS
#define BLOCK 256
#define ZSTR 68            // padded row stride for zS (floats)
#define ESTR 260           // padded row stride for eT (floats)
#define DCHUNKS (DIM / DC)                    // 32
#define NSTAGES (DCHUNKS * (K_CODES / KT))    // 256

// ---------------- e_sq precompute: one wave per code ----------------
__global__ __launch_bounds__(256)
void vq_esq_kernel(const float* __restrict__ emb, float* __restrict__ esq) {
    int w = threadIdx.x >> 6;
    int lane = threadIdx.x & 63;
    int k = blockIdx.x * 4 + w;
    float4 v = *(const float4*)&emb[(size_t)k * DIM + lane * 4];
    float s = v.x * v.x + v.y * v.y + v.z * v.z + v.w * v.w;
    #pragma unroll
    for (int off = 32; off >= 1; off >>= 1) s += __shfl_xor(s, off, 64);
    if (lane == 0) esq[k] = s;
}

// ---------------- main fused kernel ----------------
// DC=8, LDS ~21.5 KB. launch_bounds(256,4): 128-VGPR budget — the kernel
// needs ~120 live regs (acc 64 + frags 16 + prefetch 12 + argmin 16 + addr);
// (256,6) forced a 40-VGPR fit and spilled acc to scratch (86 GB HBM traffic,
// 17 ms). Occupancy 4 blocks/CU (50%) is the no-spill maximum here.
__global__ __launch_bounds__(BLOCK, 4)
void vq_main_kernel(const float* __restrict__ z,
                    const float* __restrict__ emb,
                    const float* __restrict__ esq,
                    float* __restrict__ out,
                    float* __restrict__ loss_acc) {
    __shared__ float zS[2][DC][ZSTR];
    __shared__ float eT[2][DC][ESTR];
    __shared__ float zsq_s[MT];
    __shared__ int   best_s[MT];
    __shared__ float lred[4];

    const int tid = threadIdx.x;
    const int m0  = blockIdx.x * MT;
    const int rg  = tid >> 5;   // 0..7  : rows 8*rg..8*rg+7
    const int cg  = tid & 31;   // 0..31 : codes 4*cg(+128)
    const int s1  = tid & 1;    // staging float4 slot within 8-d chunk
    const int sc  = tid >> 1;   // staging code (0..127) / z-row (0..63 for tid<128)

    // ---- z_sq for the block's 64 rows (4 threads per row) ----
    {
        int r = tid >> 2, q = tid & 3;
        const float* zr = &z[(size_t)(m0 + r) * DIM + q * 64];
        float s = 0.f;
        #pragma unroll
        for (int d4 = 0; d4 < 16; ++d4) {
            float4 v = *(const float4*)&zr[d4 * 4];
            s += v.x * v.x; s += v.y * v.y; s += v.z * v.z; s += v.w * v.w;
        }
        s += __shfl_down(s, 2, 64);
        s += __shfl_down(s, 1, 64);
        if (q == 0) zsq_s[r] = s;
    }

    // ---- stage 0 into buffer 0 ----
    {
        float4 e0 = *(const float4*)&emb[(size_t)(sc      ) * DIM + 4 * s1];
        float4 e1 = *(const float4*)&emb[(size_t)(sc + 128) * DIM + 4 * s1];
        eT[0][4 * s1 + 0][sc      ] = e0.x;
        eT[0][4 * s1 + 1][sc      ] = e0.y;
        eT[0][4 * s1 + 2][sc      ] = e0.z;
        eT[0][4 * s1 + 3][sc      ] = e0.w;
        eT[0][4 * s1 + 0][sc + 128] = e1.x;
        eT[0][4 * s1 + 1][sc + 128] = e1.y;
        eT[0][4 * s1 + 2][sc + 128] = e1.z;
        eT[0][4 * s1 + 3][sc + 128] = e1.w;
        if (tid < 128) {
            float4 zv = *(const float4*)&z[(size_t)(m0 + sc) * DIM + 4 * s1];
            zS[0][4 * s1 + 0][sc] = zv.x;
            zS[0][4 * s1 + 1][sc] = zv.y;
            zS[0][4 * s1 + 2][sc] = zv.z;
            zS[0][4 * s1 + 3][sc] = zv.w;
        }
    }
    __syncthreads();

    float bestv[8];
    int   besti[8];
    #pragma unroll
    for (int j = 0; j < 8; ++j) { bestv[j] = FLT_MAX; besti[j] = 0; }

    float acc[8][8];

    for (int s = 0; s < NSTAGES; ++s) {
        const int p     = s & 1;
        const int kt    = (s >> 5) * KT;
        const int dcIdx = s & (DCHUNKS - 1);

        if (dcIdx == 0) {
            #pragma unroll
            for (int j = 0; j < 8; ++j)
                #pragma unroll
                for (int i = 0; i < 8; ++i) acc[j][i] = 0.f;
        }

        // ---- prefetch stage s+1 (global -> regs); uniform clamp on last ----
        const int sn  = (s + 1 < NSTAGES) ? s + 1 : s;
        const int nkt = (sn >> 5) * KT;
        const int ndc = (sn & (DCHUNKS - 1)) * DC;
        float4 en0 = *(const float4*)&emb[(size_t)(nkt + sc      ) * DIM + ndc + 4 * s1];
        float4 en1 = *(const float4*)&emb[(size_t)(nkt + sc + 128) * DIM + ndc + 4 * s1];
        float4 zn;
        if (tid < 128)
            zn = *(const float4*)&z[(size_t)(m0 + sc) * DIM + ndc + 4 * s1];

        // ---- compute stage s ----
        #pragma unroll
        for (int d = 0; d < DC; ++d) {
            float4 a0 = *(const float4*)&zS[p][d][8 * rg];
            float4 a1 = *(const float4*)&zS[p][d][8 * rg + 4];
            float4 b0 = *(const float4*)&eT[p][d][4 * cg];
            float4 b1 = *(const float4*)&eT[p][d][128 + 4 * cg];
            float a[8] = {a0.x, a0.y, a0.z, a0.w, a1.x, a1.y, a1.z, a1.w};
            float b[8] = {b0.x, b0.y, b0.z, b0.w, b1.x, b1.y, b1.z, b1.w};
            #pragma unroll
            for (int j = 0; j < 8; ++j)
                #pragma unroll
                for (int i = 0; i < 8; ++i)
                    acc[j][i] = fmaf(a[j], b[i], acc[j][i]);
        }

        // ---- write prefetched stage into the other buffer ----
        {
            const int q = p ^ 1;
            eT[q][4 * s1 + 0][sc      ] = en0.x;
            eT[q][4 * s1 + 1][sc      ] = en0.y;
            eT[q][4 * s1 + 2][sc      ] = en0.z;
            eT[q][4 * s1 + 3][sc      ] = en0.w;
            eT[q][4 * s1 + 0][sc + 128] = en1.x;
            eT[q][4 * s1 + 1][sc + 128] = en1.y;
            eT[q][4 * s1 + 2][sc + 128] = en1.z;
            eT[q][4 * s1 + 3][sc + 128] = en1.w;
            if (tid < 128) {
                zS[q][4 * s1 + 0][sc] = zn.x;
                zS[q][4 * s1 + 1][sc] = zn.y;
                zS[q][4 * s1 + 2][sc] = zn.z;
                zS[q][4 * s1 + 3][sc] = zn.w;
            }
        }

        // ---- end of k-tile: literal f32 distance + running argmin ----
        if (dcIdx == DCHUNKS - 1) {
            float4 e0 = *(const float4*)&esq[kt + 4 * cg];
            float4 e1 = *(const float4*)&esq[kt + 128 + 4 * cg];
            float es[8] = {e0.x, e0.y, e0.z, e0.w, e1.x, e1.y, e1.z, e1.w};
            #pragma unroll
            for (int j = 0; j < 8; ++j) {
                float zs = zsq_s[8 * rg + j];
                #pragma unroll
                for (int i = 0; i < 8; ++i) {
                    float t    = zs + es[i];             // fl(z_sq + e_sq)
                    float dist = t - 2.0f * acc[j][i];   // fl(t - 2*cross)
                    int idx = (i < 4) ? (kt + 4 * cg + i) : (kt + 128 + 4 * cg + (i - 4));
                    bool better = (dist < bestv[j]);
                    bestv[j] = better ? dist : bestv[j];
                    besti[j] = better ? idx  : besti[j];
                }
            }
        }
        __syncthreads();
    }

    // cross-lane argmin over the 32 code-group lanes (lexicographic: val, idx)
    #pragma unroll
    for (int off = 16; off >= 1; off >>= 1) {
        #pragma unroll
        for (int j = 0; j < 8; ++j) {
            float ov = __shfl_xor(bestv[j], off, 64);
            int   oi = __shfl_xor(besti[j], off, 64);
            bool take = (ov < bestv[j]) || (ov == bestv[j] && oi < besti[j]);
            bestv[j] = take ? ov : bestv[j];
            besti[j] = take ? oi : besti[j];
        }
    }
    if (cg == 0) {
        #pragma unroll
        for (int j = 0; j < 8; ++j) best_s[8 * rg + j] = besti[j];
    }
    __syncthreads();

    // ---- epilogue: z_q_st (straight-through), loss partial, indices ----
    float lsum = 0.f;
    const int d4 = tid & 63;
    for (int it = 0; it < 16; ++it) {
        int r  = (tid >> 6) + it * 4;
        int bk = best_s[r];
        float4 q4 = *(const float4*)&emb[(size_t)bk * DIM + 4 * d4];
        float4 z4 = *(const float4*)&z[(size_t)(m0 + r) * DIM + 4 * d4];
        float4 o;
        float dx;
        dx = q4.x - z4.x; o.x = z4.x + dx; lsum = fmaf(dx, dx, lsum);
        dx = q4.y - z4.y; o.y = z4.y + dx; lsum = fmaf(dx, dx, lsum);
        dx = q4.z - z4.z; o.z = z4.z + dx; lsum = fmaf(dx, dx, lsum);
        dx = q4.w - z4.w; o.w = z4.w + dx; lsum = fmaf(dx, dx, lsum);
        *(float4*)&out[(size_t)(m0 + r) * DIM + 4 * d4] = o;
    }
    #pragma unroll
    for (int off = 32; off >= 1; off >>= 1) lsum += __shfl_xor(lsum, off, 64);
    if ((tid & 63) == 0) lred[tid >> 6] = lsum;
    __syncthreads();
    if (tid == 0) {
        float bs = lred[0] + lred[1] + lred[2] + lred[3];
        atomicAdd(loss_acc, bs);
    }
    // indices as float32 values
    if (tid < MT) out[(size_t)N_ROWS * DIM + 1 + m0 + tid] = (float)best_s[tid];
}

// ---------------- finalize: vq_loss = 1.25 * mean ----------------
__global__ void vq_finalize_kernel(const float* __restrict__ loss_acc,
                                   float* __restrict__ out) {
    double s = (double)loss_acc[0];
    out[(size_t)N_ROWS * DIM] = (float)(s * 1.25 / ((double)N_ROWS * (double)DIM));
}

extern "C" void kernel_launch(void* const* d_in, const int* in_sizes, int n_in,
                              void* d_out, int out_size, void* d_ws, size_t ws_size,
                              hipStream_t stream) {
    (void)in_sizes; (void)n_in; (void)out_size; (void)ws_size;
    const float* z   = (const float*)d_in[0];
    const float* emb = (const float*)d_in[1];
    float* out = (float*)d_out;
    float* ws  = (float*)d_ws;
    float* loss_acc = ws;        // ws[0]
    float* esq      = ws + 64;   // 2048 floats

    hipMemsetAsync(d_ws, 0, sizeof(float), stream);
    vq_esq_kernel<<<K_CODES / 4, 256, 0, stream>>>(emb, esq);
    vq_main_kernel<<<N_ROWS / MT, BLOCK, 0, stream>>>(z, emb, esq, out, loss_acc);
    vq_finalize_kernel<<<1, 1, 0, stream>>>(loss_acc, out);
}